// Round 8
// baseline (299.441 us; speedup 1.0000x reference)
//
#include <hip/hip_runtime.h>
#include <hip/hip_bf16.h>

// GCN stack: N=50000 nodes, E=600000 edges, D=128.
//  1. prep0: zero cnt + (W1,R1,W2,R2 -> f16 transposed; Wc=W3@Wh -> f16 T)
//  2. hist col -> cnt; hierarchical scan -> row_ptr/cursor (+dinv); fill CSR
//     by dest (entry 4B: low16=src, high16=f16 norm)
//  3. gemm_dual<1>: x -> H1(B0h), XR1(B1h)
//     spmm_gemm<1>: x1=relu(A·H1+XR1) kept in LDS -> H2(B3h), XR2(B2h)
//     spmm_gemm<0>: x2=relu(A·H2+XR2) kept in LDS -> G=x2@Wc (B0h)
//     spmm_final:   out = A·G + bh (fp32 into d_out)
//
// R1: single-block scan -> hierarchical (634->542)
// R2: fp32 VALU GEMM -> f16 MFMA; SpMM unroll x4 (542->422)
// R3: all activations f16 (422->340)
// R4: SpMM 16B/lane + dual-GEMM fusion (340->317)
// R5: head folded into Wc=W3@Wh (317->316)
// R6: SpMM 1 node/16-lane sub; csr 8B->4B (316->296)
// R7: SpMM+GEMM block-local fusion (x1,x2 never touch HBM); prep merged.
//     13 -> 10 dispatches.

#define SCAN_CHUNK 1024

typedef _Float16 half8 __attribute__((ext_vector_type(8)));
typedef _Float16 half4 __attribute__((ext_vector_type(4)));
typedef float floatx4 __attribute__((ext_vector_type(4)));

// blocks [0, nzb): zero cnt. blocks [nzb, nzb+64): wcvt. [nzb+64, nzb+80): Wc.
__global__ __launch_bounds__(256) void prep0_kernel(
        int* __restrict__ cnt, int n, int nzb,
        const float* __restrict__ W1, const float* __restrict__ R1,
        const float* __restrict__ W2, const float* __restrict__ R2,
        const float* __restrict__ W3, const float* __restrict__ Wh,
        _Float16* __restrict__ Wt) {
    int b = blockIdx.x;
    int t = threadIdx.x;
    if (b < nzb) {
        int i = b * 256 + t;
        if (i < n) cnt[i] = 0;
        return;
    }
    int b2 = b - nzb;
    if (b2 < 64) {
        __shared__ float tile[32][33];
        int mat = b2 >> 4, tl = b2 & 15;
        const float* W = (mat == 0) ? W1 : (mat == 1) ? R1 : (mat == 2) ? W2 : R2;
        _Float16* T = Wt + (size_t)mat * 16384;
        int tr = (tl >> 2) * 32, tc = (tl & 3) * 32;
        int i = t >> 3, j4 = t & 7;
        float4 v = *(const float4*)&W[(tr + i) * 128 + tc + j4 * 4];
        tile[i][j4 * 4 + 0] = v.x;
        tile[i][j4 * 4 + 1] = v.y;
        tile[i][j4 * 4 + 2] = v.z;
        tile[i][j4 * 4 + 3] = v.w;
        __syncthreads();
        half4 h;
        h.x = (_Float16)tile[j4 * 4 + 0][i];
        h.y = (_Float16)tile[j4 * 4 + 1][i];
        h.z = (_Float16)tile[j4 * 4 + 2][i];
        h.w = (_Float16)tile[j4 * 4 + 3][i];
        *(half4*)&T[(tc + i) * 128 + tr + j4 * 4] = h;
    } else {
        int bb = b2 - 64;
        _Float16* Wtc = Wt + (size_t)4 * 16384;
        int c = bb * 8 + (t >> 5);
        int k0 = (t & 31) * 4;
        float acc0 = 0.f, acc1 = 0.f, acc2 = 0.f, acc3 = 0.f;
        for (int j = 0; j < 128; ++j) {
            float wh = Wh[j * 128 + c];
            acc0 = fmaf(W3[(k0 + 0) * 128 + j], wh, acc0);
            acc1 = fmaf(W3[(k0 + 1) * 128 + j], wh, acc1);
            acc2 = fmaf(W3[(k0 + 2) * 128 + j], wh, acc2);
            acc3 = fmaf(W3[(k0 + 3) * 128 + j], wh, acc3);
        }
        half4 h;
        h.x = (_Float16)acc0; h.y = (_Float16)acc1;
        h.z = (_Float16)acc2; h.w = (_Float16)acc3;
        *(half4*)&Wtc[c * 128 + k0] = h;
    }
}

__global__ void hist_kernel(const int* __restrict__ col, int* __restrict__ cnt, int E) {
    int i = blockIdx.x * blockDim.x + threadIdx.x;
    if (i < E) atomicAdd(&cnt[col[i]], 1);
}

__global__ __launch_bounds__(256) void scan_reduce_kernel(
        const int* __restrict__ cnt, int* __restrict__ bsum, int n) {
    __shared__ int s[256];
    int b = blockIdx.x, t = threadIdx.x;
    int base = b * SCAN_CHUNK + t * 4;
    int v = 0;
    if (base + 3 < n) {
        int4 q = *(const int4*)&cnt[base];
        v = q.x + q.y + q.z + q.w;
    } else {
        for (int i = 0; i < 4; ++i) if (base + i < n) v += cnt[base + i];
    }
    s[t] = v;
    __syncthreads();
    for (int off = 128; off > 0; off >>= 1) {
        if (t < off) s[t] += s[t + off];
        __syncthreads();
    }
    if (t == 0) bsum[b] = s[0];
}

__global__ __launch_bounds__(1024) void scan_bsum_kernel(
        const int* __restrict__ bsum, int* __restrict__ boff, int nb) {
    __shared__ int s[1024];
    int t = threadIdx.x;
    s[t] = (t < nb) ? bsum[t] : 0;
    __syncthreads();
    for (int off = 1; off < 1024; off <<= 1) {
        int add = (t >= off) ? s[t - off] : 0;
        __syncthreads();
        s[t] += add;
        __syncthreads();
    }
    if (t < nb) boff[t] = (t == 0) ? 0 : s[t - 1];
}

// scan chunk write + dinv = rsqrt(cnt+1) folded in
__global__ __launch_bounds__(256) void scan_write_kernel(
        const int* __restrict__ cnt, const int* __restrict__ boff,
        int* __restrict__ row_ptr, int* __restrict__ cursor,
        float* __restrict__ dinv, int n, int E) {
    __shared__ int s[256];
    int b = blockIdx.x, t = threadIdx.x;
    int base = b * SCAN_CHUNK + t * 4;
    int v[4];
    int sum = 0;
    for (int i = 0; i < 4; ++i) {
        v[i] = (base + i < n) ? cnt[base + i] : 0;
        sum += v[i];
    }
    s[t] = sum;
    __syncthreads();
    for (int off = 1; off < 256; off <<= 1) {
        int add = (t >= off) ? s[t - off] : 0;
        __syncthreads();
        s[t] += add;
        __syncthreads();
    }
    int prefix = boff[b] + ((t == 0) ? 0 : s[t - 1]);
    for (int i = 0; i < 4; ++i) {
        if (base + i < n) {
            row_ptr[base + i] = prefix;
            cursor[base + i] = prefix;
            dinv[base + i] = rsqrtf((float)(v[i] + 1));
            prefix += v[i];
        }
    }
    if (b == 0 && t == 0) row_ptr[n] = E;
}

// csr entry: low16 = src node id (N<65536), high16 = f16 norm
__global__ void fill_kernel(const int* __restrict__ row, const int* __restrict__ colv,
                            const float* __restrict__ dinv, int* __restrict__ cursor,
                            unsigned* __restrict__ csr, int E) {
    int i = blockIdx.x * blockDim.x + threadIdx.x;
    if (i < E) {
        int r = row[i], c = colv[i];
        int p = atomicAdd(&cursor[c], 1);
        _Float16 nrm = (_Float16)(dinv[r] * dinv[c]);
        unsigned hn = (unsigned)__builtin_bit_cast(unsigned short, nrm);
        csr[p] = (unsigned)r | (hn << 16);
    }
}

// Dual GEMM from global A: outA = X@WA, outB = X@WB (fp32 X cvt in staging).
// Fragment layouts (HW-verified, guide §3): A[m=lane&15][k=quad*8+j],
// B[k=quad*8+j][n=lane&15], C/D col=lane&15 row=quad*4+reg.
__global__ __launch_bounds__(256) void gemm_dual_f32_kernel(
        const float* __restrict__ X, const _Float16* __restrict__ WtA,
        const _Float16* __restrict__ WtB, _Float16* __restrict__ outA,
        _Float16* __restrict__ outB, int n) {
    __shared__ _Float16 Af[64 * 136];
    __shared__ _Float16 Bt[128 * 136];
    int t = threadIdx.x;
    int r0 = blockIdx.x * 64;

#pragma unroll
    for (int i = 0; i < 8; ++i) {
        int flat = i * 256 + t;
        int r = flat >> 5, c4 = flat & 31;
        float4 v = make_float4(0.f, 0.f, 0.f, 0.f);
        if (r0 + r < n) v = ((const float4*)X)[(size_t)(r0 + r) * 32 + c4];
        half4 h;
        h.x = (_Float16)v.x; h.y = (_Float16)v.y;
        h.z = (_Float16)v.z; h.w = (_Float16)v.w;
        *(half4*)&Af[r * 136 + c4 * 4] = h;
    }
#pragma unroll
    for (int i = 0; i < 8; ++i) {
        int flat = i * 256 + t;
        int c = flat >> 4, k8 = flat & 15;
        *(half8*)&Bt[c * 136 + k8 * 8] = *(const half8*)&WtA[c * 128 + k8 * 8];
    }
    __syncthreads();

    int lane = t & 63, w = t >> 6;
    int m = lane & 15, q = lane >> 4;
    int rowb = r0 + w * 16 + q * 4;

    half8 a[4];
#pragma unroll
    for (int s = 0; s < 4; ++s)
        a[s] = *(const half8*)&Af[(w * 16 + m) * 136 + s * 32 + q * 8];

    floatx4 acc[8];
#pragma unroll
    for (int nt = 0; nt < 8; ++nt) acc[nt] = (floatx4){0.f, 0.f, 0.f, 0.f};
#pragma unroll
    for (int s = 0; s < 4; ++s)
#pragma unroll
        for (int nt = 0; nt < 8; ++nt) {
            half8 b = *(const half8*)&Bt[(nt * 16 + m) * 136 + s * 32 + q * 8];
            acc[nt] = __builtin_amdgcn_mfma_f32_16x16x32_f16(a[s], b, acc[nt], 0, 0, 0);
        }
    __syncthreads();
#pragma unroll
    for (int i = 0; i < 8; ++i) {
        int flat = i * 256 + t;
        int c = flat >> 4, k8 = flat & 15;
        *(half8*)&Bt[c * 136 + k8 * 8] = *(const half8*)&WtB[c * 128 + k8 * 8];
    }
#pragma unroll
    for (int nt = 0; nt < 8; ++nt) {
        int col = nt * 16 + m;
#pragma unroll
        for (int r = 0; r < 4; ++r) {
            int gr = rowb + r;
            if (gr < n) outA[(size_t)gr * 128 + col] = (_Float16)acc[nt][r];
        }
    }
    __syncthreads();

#pragma unroll
    for (int nt = 0; nt < 8; ++nt) acc[nt] = (floatx4){0.f, 0.f, 0.f, 0.f};
#pragma unroll
    for (int s = 0; s < 4; ++s)
#pragma unroll
        for (int nt = 0; nt < 8; ++nt) {
            half8 b = *(const half8*)&Bt[(nt * 16 + m) * 136 + s * 32 + q * 8];
            acc[nt] = __builtin_amdgcn_mfma_f32_16x16x32_f16(a[s], b, acc[nt], 0, 0, 0);
        }
#pragma unroll
    for (int nt = 0; nt < 8; ++nt) {
        int col = nt * 16 + m;
#pragma unroll
        for (int r = 0; r < 4; ++r) {
            int gr = rowb + r;
            if (gr < n) outB[(size_t)gr * 128 + col] = (_Float16)acc[nt][r];
        }
    }
}

// Fused SpMM -> GEMM. Block owns nodes r0..r0+63. Phase 1: x_l =
// relu(A·h + xr) for own nodes, fp32 accum, written f16 straight into the
// Af LDS tile (never to HBM). Phase 2: standard (dual) GEMM from Af.
// Safety: gathers read h (prev-kernel output, read-only here); xr is
// node-local (own rows only); outputs go to buffers disjoint from h/xr.
template <int DUAL>
__global__ __launch_bounds__(256) void spmm_gemm_kernel(
        const _Float16* __restrict__ h, const _Float16* __restrict__ xr,
        const int* __restrict__ row_ptr, const unsigned* __restrict__ csr,
        const float* __restrict__ dinv,
        const _Float16* __restrict__ WtA, const _Float16* __restrict__ WtB,
        _Float16* __restrict__ outA, _Float16* __restrict__ outB, int n) {
    __shared__ _Float16 Af[64 * 136];
    __shared__ _Float16 Bt[128 * 136];
    int t = threadIdx.x;
    int r0 = blockIdx.x * 64;
    const half8* hp8 = (const half8*)h;

    // stage B (WtA) first so its loads are in flight during the SpMM phase
#pragma unroll
    for (int i = 0; i < 8; ++i) {
        int flat = i * 256 + t;
        int c = flat >> 4, k8 = flat & 15;
        *(half8*)&Bt[c * 136 + k8 * 8] = *(const half8*)&WtA[c * 128 + k8 * 8];
    }

    // SpMM phase: 16 lanes per node, 4 passes cover 64 nodes
    int fl = t & 15;
#pragma unroll
    for (int it = 0; it < 4; ++it) {
        int lr = it * 16 + (t >> 4);
        int node = r0 + lr;
        float acc[8];
#pragma unroll
        for (int j = 0; j < 8; ++j) acc[j] = 0.f;
        if (node < n) {
            int e0 = row_ptr[node], e1 = row_ptr[node + 1];
            for (int e = e0; e < e1; e += 4) {
                int i1 = e + 1, i2 = e + 2, i3 = e + 3;
                int a1 = i1 < e1, a2 = i2 < e1, a3 = i3 < e1;
                unsigned d0 = csr[e];
                unsigned d1 = csr[a1 ? i1 : e];
                unsigned d2 = csr[a2 ? i2 : e];
                unsigned d3 = csr[a3 ? i3 : e];
                half8 v0 = hp8[(size_t)(d0 & 0xffffu) * 16 + fl];
                half8 v1 = hp8[(size_t)(d1 & 0xffffu) * 16 + fl];
                half8 v2 = hp8[(size_t)(d2 & 0xffffu) * 16 + fl];
                half8 v3 = hp8[(size_t)(d3 & 0xffffu) * 16 + fl];
                float n0 = (float)__builtin_bit_cast(_Float16, (unsigned short)(d0 >> 16));
                float n1 = a1 ? (float)__builtin_bit_cast(_Float16, (unsigned short)(d1 >> 16)) : 0.f;
                float n2 = a2 ? (float)__builtin_bit_cast(_Float16, (unsigned short)(d2 >> 16)) : 0.f;
                float n3 = a3 ? (float)__builtin_bit_cast(_Float16, (unsigned short)(d3 >> 16)) : 0.f;
#pragma unroll
                for (int j = 0; j < 8; ++j) {
                    acc[j] = fmaf(n0, (float)v0[j], acc[j]);
                    acc[j] = fmaf(n1, (float)v1[j], acc[j]);
                    acc[j] = fmaf(n2, (float)v2[j], acc[j]);
                    acc[j] = fmaf(n3, (float)v3[j], acc[j]);
                }
            }
            float di = dinv[node];
            float w = di * di;
            half8 hv = hp8[(size_t)node * 16 + fl];
            half8 r = ((const half8*)xr)[(size_t)node * 16 + fl];
#pragma unroll
            for (int j = 0; j < 8; ++j) {
                acc[j] = fmaf(w, (float)hv[j], acc[j]);
                acc[j] += (float)r[j];
                acc[j] = fmaxf(acc[j], 0.f);   // relu
            }
        }
        half8 o;
#pragma unroll
        for (int j = 0; j < 8; ++j) o[j] = (_Float16)acc[j];
        *(half8*)&Af[lr * 136 + fl * 8] = o;
    }
    __syncthreads();

    // GEMM phase
    int lane = t & 63, w = t >> 6;
    int m = lane & 15, q = lane >> 4;
    int rowb = r0 + w * 16 + q * 4;

    half8 a[4];
#pragma unroll
    for (int s = 0; s < 4; ++s)
        a[s] = *(const half8*)&Af[(w * 16 + m) * 136 + s * 32 + q * 8];

    floatx4 acc[8];
#pragma unroll
    for (int nt = 0; nt < 8; ++nt) acc[nt] = (floatx4){0.f, 0.f, 0.f, 0.f};
#pragma unroll
    for (int s = 0; s < 4; ++s)
#pragma unroll
        for (int nt = 0; nt < 8; ++nt) {
            half8 b = *(const half8*)&Bt[(nt * 16 + m) * 136 + s * 32 + q * 8];
            acc[nt] = __builtin_amdgcn_mfma_f32_16x16x32_f16(a[s], b, acc[nt], 0, 0, 0);
        }

    if (DUAL) {
        __syncthreads();
#pragma unroll
        for (int i = 0; i < 8; ++i) {
            int flat = i * 256 + t;
            int c = flat >> 4, k8 = flat & 15;
            *(half8*)&Bt[c * 136 + k8 * 8] = *(const half8*)&WtB[c * 128 + k8 * 8];
        }
    }
#pragma unroll
    for (int nt = 0; nt < 8; ++nt) {
        int col = nt * 16 + m;
#pragma unroll
        for (int r = 0; r < 4; ++r) {
            int gr = rowb + r;
            if (gr < n) outA[(size_t)gr * 128 + col] = (_Float16)acc[nt][r];
        }
    }
    if (DUAL) {
        __syncthreads();
#pragma unroll
        for (int nt = 0; nt < 8; ++nt) acc[nt] = (floatx4){0.f, 0.f, 0.f, 0.f};
#pragma unroll
        for (int s = 0; s < 4; ++s)
#pragma unroll
            for (int nt = 0; nt < 8; ++nt) {
                half8 b = *(const half8*)&Bt[(nt * 16 + m) * 136 + s * 32 + q * 8];
                acc[nt] = __builtin_amdgcn_mfma_f32_16x16x32_f16(a[s], b, acc[nt], 0, 0, 0);
            }
#pragma unroll
        for (int nt = 0; nt < 8; ++nt) {
            int col = nt * 16 + m;
#pragma unroll
            for (int r = 0; r < 4; ++r) {
                int gr = rowb + r;
                if (gr < n) outB[(size_t)gr * 128 + col] = (_Float16)acc[nt][r];
            }
        }
    }
}

// Final SpMM: one 16-lane sub-group per node, no residual/relu, writes
// fp32 + bias into d_out (head already folded into Wc).
__global__ void spmm_final_kernel(const _Float16* __restrict__ h,
                                  const int* __restrict__ row_ptr,
                                  const unsigned* __restrict__ csr,
                                  const float* __restrict__ dinv,
                                  float* __restrict__ outf,
                                  const float* __restrict__ bias, int n) {
    int gid = blockIdx.x * blockDim.x + threadIdx.x;
    int node = gid >> 4;
    int fl = gid & 15;
    if (node >= n) return;
    const half8* hp8 = (const half8*)h;

    float acc[8];
#pragma unroll
    for (int j = 0; j < 8; ++j) acc[j] = 0.f;

    int e0 = row_ptr[node], e1 = row_ptr[node + 1];
    for (int e = e0; e < e1; e += 4) {
        int i1 = e + 1, i2 = e + 2, i3 = e + 3;
        int a1 = i1 < e1, a2 = i2 < e1, a3 = i3 < e1;
        unsigned d0 = csr[e];
        unsigned d1 = csr[a1 ? i1 : e];
        unsigned d2 = csr[a2 ? i2 : e];
        unsigned d3 = csr[a3 ? i3 : e];
        half8 v0 = hp8[(size_t)(d0 & 0xffffu) * 16 + fl];
        half8 v1 = hp8[(size_t)(d1 & 0xffffu) * 16 + fl];
        half8 v2 = hp8[(size_t)(d2 & 0xffffu) * 16 + fl];
        half8 v3 = hp8[(size_t)(d3 & 0xffffu) * 16 + fl];
        float n0 = (float)__builtin_bit_cast(_Float16, (unsigned short)(d0 >> 16));
        float n1 = a1 ? (float)__builtin_bit_cast(_Float16, (unsigned short)(d1 >> 16)) : 0.f;
        float n2 = a2 ? (float)__builtin_bit_cast(_Float16, (unsigned short)(d2 >> 16)) : 0.f;
        float n3 = a3 ? (float)__builtin_bit_cast(_Float16, (unsigned short)(d3 >> 16)) : 0.f;
#pragma unroll
        for (int j = 0; j < 8; ++j) {
            acc[j] = fmaf(n0, (float)v0[j], acc[j]);
            acc[j] = fmaf(n1, (float)v1[j], acc[j]);
            acc[j] = fmaf(n2, (float)v2[j], acc[j]);
            acc[j] = fmaf(n3, (float)v3[j], acc[j]);
        }
    }

    float di = dinv[node];
    float w = di * di;
    half8 hv = hp8[(size_t)node * 16 + fl];
#pragma unroll
    for (int j = 0; j < 8; ++j) acc[j] = fmaf(w, (float)hv[j], acc[j]);

    float4 b0 = *(const float4*)&bias[fl * 8];
    float4 b1 = *(const float4*)&bias[fl * 8 + 4];
    float4 o0 = make_float4(acc[0] + b0.x, acc[1] + b0.y,
                            acc[2] + b0.z, acc[3] + b0.w);
    float4 o1 = make_float4(acc[4] + b1.x, acc[5] + b1.y,
                            acc[6] + b1.z, acc[7] + b1.w);
    ((float4*)outf)[(size_t)node * 32 + fl * 2] = o0;
    ((float4*)outf)[(size_t)node * 32 + fl * 2 + 1] = o1;
}

extern "C" void kernel_launch(void* const* d_in, const int* in_sizes, int n_in,
                              void* d_out, int out_size, void* d_ws, size_t ws_size,
                              hipStream_t stream) {
    const float* x  = (const float*)d_in[0];
    const int*   ei = (const int*)d_in[1];
    const float* W1 = (const float*)d_in[2];
    const float* R1 = (const float*)d_in[3];
    const float* W2 = (const float*)d_in[4];
    const float* R2 = (const float*)d_in[5];
    const float* W3 = (const float*)d_in[6];
    const float* Wh = (const float*)d_in[7];
    const float* bh = (const float*)d_in[8];
    float* out = (float*)d_out;

    int N = in_sizes[0] / 128;
    int E = in_sizes[1] / 2;

    char* p = (char*)d_ws;
    auto alloc = [&](size_t bytes) {
        char* r = p;
        p += (bytes + 255) & ~(size_t)255;
        return r;
    };
    int*      cnt     = (int*)alloc((size_t)N * 4);
    int*      row_ptr = (int*)alloc((size_t)(N + 1) * 4);
    int*      cursor  = (int*)alloc((size_t)N * 4);
    float*    dinv    = (float*)alloc((size_t)N * 4);
    int*      bsum    = (int*)alloc((size_t)1024 * 4);
    int*      boff    = (int*)alloc((size_t)1024 * 4);
    unsigned* csr     = (unsigned*)alloc((size_t)E * 4);
    _Float16* Wt      = (_Float16*)alloc((size_t)5 * 16384 * 2);
    _Float16* B0h     = (_Float16*)alloc((size_t)N * 128 * 2);
    _Float16* B1h     = (_Float16*)alloc((size_t)N * 128 * 2);
    _Float16* B2h     = (_Float16*)alloc((size_t)N * 128 * 2);
    _Float16* B3h     = (_Float16*)alloc((size_t)N * 128 * 2);

    const int* rowi = ei;
    const int* coli = ei + E;

    int nb = (N + SCAN_CHUNK - 1) / SCAN_CHUNK;
    int nzb = (N + 255) / 256;

    prep0_kernel<<<nzb + 80, 256, 0, stream>>>(cnt, N, nzb, W1, R1, W2, R2, W3, Wh, Wt);
    hist_kernel<<<(E + 255) / 256, 256, 0, stream>>>(coli, cnt, E);
    scan_reduce_kernel<<<nb, 256, 0, stream>>>(cnt, bsum, N);
    scan_bsum_kernel<<<1, 1024, 0, stream>>>(bsum, boff, nb);
    scan_write_kernel<<<nb, 256, 0, stream>>>(cnt, boff, row_ptr, cursor, dinv, N, E);
    fill_kernel<<<(E + 255) / 256, 256, 0, stream>>>(rowi, coli, dinv, cursor, csr, E);

    int gb = (N + 63) / 64;
    int sb = ((size_t)N * 16 + 255) / 256;
    _Float16* Wt1 = Wt;
    _Float16* Rt1 = Wt + 16384;
    _Float16* Wt2 = Wt + 2 * 16384;
    _Float16* Rt2 = Wt + 3 * 16384;
    _Float16* Wtc = Wt + 4 * 16384;

    // layer 1 GEMMs: x -> H1(B0h), XR1(B1h)
    gemm_dual_f32_kernel<<<gb, 256, 0, stream>>>(x, Wt1, Rt1, B0h, B1h, N);
    // spmm1 (x1 in LDS) + layer-2 dual GEMM: -> H2(B3h), XR2(B2h)
    spmm_gemm_kernel<1><<<gb, 256, 0, stream>>>(B0h, B1h, row_ptr, csr, dinv,
                                                Wt2, Rt2, B3h, B2h, N);
    // spmm2 (x2 in LDS) + G = x2@Wc: -> B0h
    spmm_gemm_kernel<0><<<gb, 256, 0, stream>>>(B3h, B2h, row_ptr, csr, dinv,
                                                Wtc, nullptr, B0h, nullptr, N);
    // final: out = A·G + bh (fp32)
    spmm_final_kernel<<<sb, 256, 0, stream>>>(B0h, row_ptr, csr, dinv, out, bh, N);
}

// Round 9
// 294.310 us; speedup vs baseline: 1.0174x; 1.0174x over previous
//
#include <hip/hip_runtime.h>
#include <hip/hip_bf16.h>

// GCN stack: N=50000 nodes, E=600000 edges, D=128.
//  1. prep0: zero cnt + (W1,R1,W2,R2 -> f16 transposed; Wc=W3@Wh -> f16 T)
//  2. hist col -> cnt; hierarchical scan -> row_ptr/cursor (+dinv); fill CSR
//     by dest (entry 4B: low16=src, high16=f16 norm)
//  3. gemm_dual<1>: x -> H1,XR1; spmm: x1; gemm_dual<0>: -> H2,XR2;
//     spmm: x2; gemm_h(Wc): G; spmm_final: out = A*G + bh (fp32)
//
// R1: single-block scan -> hierarchical (634->542)
// R2: fp32 VALU GEMM -> f16 MFMA; SpMM unroll x4 (542->422)
// R3: all activations f16 (422->340)
// R4: SpMM 16B/lane + dual-GEMM fusion (340->317)
// R5: head folded into Wc=W3@Wh (317->316)
// R6: SpMM 1 node/16-lane sub; csr 8B->4B (316->296)
// R7 FAILED: SpMM+GEMM fusion -> 17% occupancy (52KB LDS, 3 blk/CU) strangled
//     the latency-bound gather phase (49.7us vs ~20+7 split). Lesson: keep
//     gather kernels LDS-free / high-occupancy. (296->299)
// R8: revert fusion (R6 structure), keep prep0 merge, SpMM unroll 4->8.

#define SCAN_CHUNK 1024

typedef _Float16 half8 __attribute__((ext_vector_type(8)));
typedef _Float16 half4 __attribute__((ext_vector_type(4)));
typedef float floatx4 __attribute__((ext_vector_type(4)));

// blocks [0, nzb): zero cnt. blocks [nzb, nzb+64): wcvt. [nzb+64, nzb+80): Wc.
__global__ __launch_bounds__(256) void prep0_kernel(
        int* __restrict__ cnt, int n, int nzb,
        const float* __restrict__ W1, const float* __restrict__ R1,
        const float* __restrict__ W2, const float* __restrict__ R2,
        const float* __restrict__ W3, const float* __restrict__ Wh,
        _Float16* __restrict__ Wt) {
    int b = blockIdx.x;
    int t = threadIdx.x;
    if (b < nzb) {
        int i = b * 256 + t;
        if (i < n) cnt[i] = 0;
        return;
    }
    int b2 = b - nzb;
    if (b2 < 64) {
        __shared__ float tile[32][33];
        int mat = b2 >> 4, tl = b2 & 15;
        const float* W = (mat == 0) ? W1 : (mat == 1) ? R1 : (mat == 2) ? W2 : R2;
        _Float16* T = Wt + (size_t)mat * 16384;
        int tr = (tl >> 2) * 32, tc = (tl & 3) * 32;
        int i = t >> 3, j4 = t & 7;
        float4 v = *(const float4*)&W[(tr + i) * 128 + tc + j4 * 4];
        tile[i][j4 * 4 + 0] = v.x;
        tile[i][j4 * 4 + 1] = v.y;
        tile[i][j4 * 4 + 2] = v.z;
        tile[i][j4 * 4 + 3] = v.w;
        __syncthreads();
        half4 h;
        h.x = (_Float16)tile[j4 * 4 + 0][i];
        h.y = (_Float16)tile[j4 * 4 + 1][i];
        h.z = (_Float16)tile[j4 * 4 + 2][i];
        h.w = (_Float16)tile[j4 * 4 + 3][i];
        *(half4*)&T[(tc + i) * 128 + tr + j4 * 4] = h;
    } else {
        int bb = b2 - 64;
        _Float16* Wtc = Wt + (size_t)4 * 16384;
        int c = bb * 8 + (t >> 5);
        int k0 = (t & 31) * 4;
        float acc0 = 0.f, acc1 = 0.f, acc2 = 0.f, acc3 = 0.f;
        for (int j = 0; j < 128; ++j) {
            float wh = Wh[j * 128 + c];
            acc0 = fmaf(W3[(k0 + 0) * 128 + j], wh, acc0);
            acc1 = fmaf(W3[(k0 + 1) * 128 + j], wh, acc1);
            acc2 = fmaf(W3[(k0 + 2) * 128 + j], wh, acc2);
            acc3 = fmaf(W3[(k0 + 3) * 128 + j], wh, acc3);
        }
        half4 h;
        h.x = (_Float16)acc0; h.y = (_Float16)acc1;
        h.z = (_Float16)acc2; h.w = (_Float16)acc3;
        *(half4*)&Wtc[c * 128 + k0] = h;
    }
}

__global__ void hist_kernel(const int* __restrict__ col, int* __restrict__ cnt, int E) {
    int i = blockIdx.x * blockDim.x + threadIdx.x;
    if (i < E) atomicAdd(&cnt[col[i]], 1);
}

__global__ __launch_bounds__(256) void scan_reduce_kernel(
        const int* __restrict__ cnt, int* __restrict__ bsum, int n) {
    __shared__ int s[256];
    int b = blockIdx.x, t = threadIdx.x;
    int base = b * SCAN_CHUNK + t * 4;
    int v = 0;
    if (base + 3 < n) {
        int4 q = *(const int4*)&cnt[base];
        v = q.x + q.y + q.z + q.w;
    } else {
        for (int i = 0; i < 4; ++i) if (base + i < n) v += cnt[base + i];
    }
    s[t] = v;
    __syncthreads();
    for (int off = 128; off > 0; off >>= 1) {
        if (t < off) s[t] += s[t + off];
        __syncthreads();
    }
    if (t == 0) bsum[b] = s[0];
}

__global__ __launch_bounds__(1024) void scan_bsum_kernel(
        const int* __restrict__ bsum, int* __restrict__ boff, int nb) {
    __shared__ int s[1024];
    int t = threadIdx.x;
    s[t] = (t < nb) ? bsum[t] : 0;
    __syncthreads();
    for (int off = 1; off < 1024; off <<= 1) {
        int add = (t >= off) ? s[t - off] : 0;
        __syncthreads();
        s[t] += add;
        __syncthreads();
    }
    if (t < nb) boff[t] = (t == 0) ? 0 : s[t - 1];
}

// scan chunk write + dinv = rsqrt(cnt+1) folded in
__global__ __launch_bounds__(256) void scan_write_kernel(
        const int* __restrict__ cnt, const int* __restrict__ boff,
        int* __restrict__ row_ptr, int* __restrict__ cursor,
        float* __restrict__ dinv, int n, int E) {
    __shared__ int s[256];
    int b = blockIdx.x, t = threadIdx.x;
    int base = b * SCAN_CHUNK + t * 4;
    int v[4];
    int sum = 0;
    for (int i = 0; i < 4; ++i) {
        v[i] = (base + i < n) ? cnt[base + i] : 0;
        sum += v[i];
    }
    s[t] = sum;
    __syncthreads();
    for (int off = 1; off < 256; off <<= 1) {
        int add = (t >= off) ? s[t - off] : 0;
        __syncthreads();
        s[t] += add;
        __syncthreads();
    }
    int prefix = boff[b] + ((t == 0) ? 0 : s[t - 1]);
    for (int i = 0; i < 4; ++i) {
        if (base + i < n) {
            row_ptr[base + i] = prefix;
            cursor[base + i] = prefix;
            dinv[base + i] = rsqrtf((float)(v[i] + 1));
            prefix += v[i];
        }
    }
    if (b == 0 && t == 0) row_ptr[n] = E;
}

// csr entry: low16 = src node id (N<65536), high16 = f16 norm
__global__ void fill_kernel(const int* __restrict__ row, const int* __restrict__ colv,
                            const float* __restrict__ dinv, int* __restrict__ cursor,
                            unsigned* __restrict__ csr, int E) {
    int i = blockIdx.x * blockDim.x + threadIdx.x;
    if (i < E) {
        int r = row[i], c = colv[i];
        int p = atomicAdd(&cursor[c], 1);
        _Float16 nrm = (_Float16)(dinv[r] * dinv[c]);
        unsigned hn = (unsigned)__builtin_bit_cast(unsigned short, nrm);
        csr[p] = (unsigned)r | (hn << 16);
    }
}

// Dual GEMM: outA = X@WA, outB = X@WB. A staged once (fp32->f16 if F32IN),
// A-fragments cached in regs across both B passes (LDS Bt reused).
// Fragment layouts (HW-verified, guide §3): A[m=lane&15][k=quad*8+j],
// B[k=quad*8+j][n=lane&15], C/D col=lane&15 row=quad*4+reg.
template <int F32IN>
__global__ __launch_bounds__(256) void gemm_dual_kernel(
        const void* __restrict__ Xv, const _Float16* __restrict__ WtA,
        const _Float16* __restrict__ WtB, _Float16* __restrict__ outA,
        _Float16* __restrict__ outB, int n) {
    __shared__ _Float16 Af[64 * 136];
    __shared__ _Float16 Bt[128 * 136];
    int t = threadIdx.x;
    int r0 = blockIdx.x * 64;

    if (F32IN) {
        const float* X = (const float*)Xv;
#pragma unroll
        for (int i = 0; i < 8; ++i) {
            int flat = i * 256 + t;
            int r = flat >> 5, c4 = flat & 31;
            float4 v = make_float4(0.f, 0.f, 0.f, 0.f);
            if (r0 + r < n) v = ((const float4*)X)[(size_t)(r0 + r) * 32 + c4];
            half4 h;
            h.x = (_Float16)v.x; h.y = (_Float16)v.y;
            h.z = (_Float16)v.z; h.w = (_Float16)v.w;
            *(half4*)&Af[r * 136 + c4 * 4] = h;
        }
    } else {
        const _Float16* X = (const _Float16*)Xv;
#pragma unroll
        for (int i = 0; i < 4; ++i) {
            int flat = i * 256 + t;
            int r = flat >> 4, k8 = flat & 15;
            half8 v = {0, 0, 0, 0, 0, 0, 0, 0};
            if (r0 + r < n) v = *(const half8*)&X[(size_t)(r0 + r) * 128 + k8 * 8];
            *(half8*)&Af[r * 136 + k8 * 8] = v;
        }
    }
#pragma unroll
    for (int i = 0; i < 8; ++i) {
        int flat = i * 256 + t;
        int c = flat >> 4, k8 = flat & 15;
        *(half8*)&Bt[c * 136 + k8 * 8] = *(const half8*)&WtA[c * 128 + k8 * 8];
    }
    __syncthreads();

    int lane = t & 63, w = t >> 6;
    int m = lane & 15, q = lane >> 4;
    int rowb = r0 + w * 16 + q * 4;

    half8 a[4];
#pragma unroll
    for (int s = 0; s < 4; ++s)
        a[s] = *(const half8*)&Af[(w * 16 + m) * 136 + s * 32 + q * 8];

    floatx4 acc[8];
#pragma unroll
    for (int nt = 0; nt < 8; ++nt) acc[nt] = (floatx4){0.f, 0.f, 0.f, 0.f};
#pragma unroll
    for (int s = 0; s < 4; ++s)
#pragma unroll
        for (int nt = 0; nt < 8; ++nt) {
            half8 b = *(const half8*)&Bt[(nt * 16 + m) * 136 + s * 32 + q * 8];
            acc[nt] = __builtin_amdgcn_mfma_f32_16x16x32_f16(a[s], b, acc[nt], 0, 0, 0);
        }
    __syncthreads();
    // restage Bt with WtB; epilogue-A global stores overlap the staging
#pragma unroll
    for (int i = 0; i < 8; ++i) {
        int flat = i * 256 + t;
        int c = flat >> 4, k8 = flat & 15;
        *(half8*)&Bt[c * 136 + k8 * 8] = *(const half8*)&WtB[c * 128 + k8 * 8];
    }
#pragma unroll
    for (int nt = 0; nt < 8; ++nt) {
        int col = nt * 16 + m;
#pragma unroll
        for (int r = 0; r < 4; ++r) {
            int gr = rowb + r;
            if (gr < n) outA[(size_t)gr * 128 + col] = (_Float16)acc[nt][r];
        }
    }
    __syncthreads();

#pragma unroll
    for (int nt = 0; nt < 8; ++nt) acc[nt] = (floatx4){0.f, 0.f, 0.f, 0.f};
#pragma unroll
    for (int s = 0; s < 4; ++s)
#pragma unroll
        for (int nt = 0; nt < 8; ++nt) {
            half8 b = *(const half8*)&Bt[(nt * 16 + m) * 136 + s * 32 + q * 8];
            acc[nt] = __builtin_amdgcn_mfma_f32_16x16x32_f16(a[s], b, acc[nt], 0, 0, 0);
        }
#pragma unroll
    for (int nt = 0; nt < 8; ++nt) {
        int col = nt * 16 + m;
#pragma unroll
        for (int r = 0; r < 4; ++r) {
            int gr = rowb + r;
            if (gr < n) outB[(size_t)gr * 128 + col] = (_Float16)acc[nt][r];
        }
    }
}

// Single GEMM, f16 in / f16 out.
__global__ __launch_bounds__(256) void gemm_h_kernel(
        const _Float16* __restrict__ X, const _Float16* __restrict__ Wt,
        _Float16* __restrict__ out, int n) {
    __shared__ _Float16 Af[64 * 136];
    __shared__ _Float16 Bt[128 * 136];
    int t = threadIdx.x;
    int r0 = blockIdx.x * 64;

#pragma unroll
    for (int i = 0; i < 4; ++i) {
        int flat = i * 256 + t;
        int r = flat >> 4, k8 = flat & 15;
        half8 v = {0, 0, 0, 0, 0, 0, 0, 0};
        if (r0 + r < n) v = *(const half8*)&X[(size_t)(r0 + r) * 128 + k8 * 8];
        *(half8*)&Af[r * 136 + k8 * 8] = v;
    }
#pragma unroll
    for (int i = 0; i < 8; ++i) {
        int flat = i * 256 + t;
        int c = flat >> 4, k8 = flat & 15;
        *(half8*)&Bt[c * 136 + k8 * 8] = *(const half8*)&Wt[c * 128 + k8 * 8];
    }
    __syncthreads();

    int lane = t & 63, w = t >> 6;
    int m = lane & 15, q = lane >> 4;

    floatx4 acc[8];
#pragma unroll
    for (int nt = 0; nt < 8; ++nt) acc[nt] = (floatx4){0.f, 0.f, 0.f, 0.f};

#pragma unroll
    for (int s = 0; s < 4; ++s) {
        half8 a = *(const half8*)&Af[(w * 16 + m) * 136 + s * 32 + q * 8];
#pragma unroll
        for (int nt = 0; nt < 8; ++nt) {
            half8 b = *(const half8*)&Bt[(nt * 16 + m) * 136 + s * 32 + q * 8];
            acc[nt] = __builtin_amdgcn_mfma_f32_16x16x32_f16(a, b, acc[nt], 0, 0, 0);
        }
    }

    int rowb = r0 + w * 16 + q * 4;
#pragma unroll
    for (int nt = 0; nt < 8; ++nt) {
        int col = nt * 16 + m;
#pragma unroll
        for (int r = 0; r < 4; ++r) {
            int gr = rowb + r;
            if (gr < n) out[(size_t)gr * 128 + col] = (_Float16)acc[nt][r];
        }
    }
}

// SpMM: one 16-lane sub-group per node (4 nodes/wave), no LDS -> high
// occupancy (the R7 lesson). Lane = 16B (half8) feature slice. Edge loop
// unrolled x8 with predicated tail (clamped index, nrm=0) -> 8 gathers in
// flight per row, 32 per wave.
// FINAL: write fp32 + bias into d_out (head folded); else f16 (+xr residual).
template <int RELU, int FINAL>
__global__ void spmm_kernel(const _Float16* __restrict__ h, const _Float16* __restrict__ xr,
                            const int* __restrict__ row_ptr, const unsigned* __restrict__ csr,
                            const float* __restrict__ dinv, _Float16* __restrict__ outh,
                            float* __restrict__ outf, const float* __restrict__ bias,
                            int n) {
    int gid = blockIdx.x * blockDim.x + threadIdx.x;
    int node = gid >> 4;
    int fl = gid & 15;   // feature slice: 8 f16 at fl*8
    if (node >= n) return;
    const half8* hp8 = (const half8*)h;

    float acc[8];
#pragma unroll
    for (int j = 0; j < 8; ++j) acc[j] = 0.f;

    int e0 = row_ptr[node], e1 = row_ptr[node + 1];
    for (int e = e0; e < e1; e += 8) {
        unsigned d[8];
        float nn[8];
#pragma unroll
        for (int u = 0; u < 8; ++u) {
            int idx = e + u;
            int act = idx < e1;
            d[u] = csr[act ? idx : e];
            nn[u] = act ? (float)__builtin_bit_cast(_Float16, (unsigned short)(d[u] >> 16))
                        : 0.f;
        }
        half8 v[8];
#pragma unroll
        for (int u = 0; u < 8; ++u)
            v[u] = hp8[(size_t)(d[u] & 0xffffu) * 16 + fl];
#pragma unroll
        for (int u = 0; u < 8; ++u)
#pragma unroll
            for (int j = 0; j < 8; ++j)
                acc[j] = fmaf(nn[u], (float)v[u][j], acc[j]);
    }

    // self loop
    float di = dinv[node];
    float w = di * di;
    half8 hv = hp8[(size_t)node * 16 + fl];
#pragma unroll
    for (int j = 0; j < 8; ++j) acc[j] = fmaf(w, (float)hv[j], acc[j]);
    if (!FINAL && xr) {
        half8 r = ((const half8*)xr)[(size_t)node * 16 + fl];
#pragma unroll
        for (int j = 0; j < 8; ++j) acc[j] += (float)r[j];
    }
    if (RELU) {
#pragma unroll
        for (int j = 0; j < 8; ++j) acc[j] = fmaxf(acc[j], 0.f);
    }
    if (FINAL) {
        float4 b0 = *(const float4*)&bias[fl * 8];
        float4 b1 = *(const float4*)&bias[fl * 8 + 4];
        float4 o0 = make_float4(acc[0] + b0.x, acc[1] + b0.y,
                                acc[2] + b0.z, acc[3] + b0.w);
        float4 o1 = make_float4(acc[4] + b1.x, acc[5] + b1.y,
                                acc[6] + b1.z, acc[7] + b1.w);
        ((float4*)outf)[(size_t)node * 32 + fl * 2] = o0;
        ((float4*)outf)[(size_t)node * 32 + fl * 2 + 1] = o1;
    } else {
        half8 o;
#pragma unroll
        for (int j = 0; j < 8; ++j) o[j] = (_Float16)acc[j];
        ((half8*)outh)[(size_t)node * 16 + fl] = o;
    }
}

extern "C" void kernel_launch(void* const* d_in, const int* in_sizes, int n_in,
                              void* d_out, int out_size, void* d_ws, size_t ws_size,
                              hipStream_t stream) {
    const float* x  = (const float*)d_in[0];
    const int*   ei = (const int*)d_in[1];
    const float* W1 = (const float*)d_in[2];
    const float* R1 = (const float*)d_in[3];
    const float* W2 = (const float*)d_in[4];
    const float* R2 = (const float*)d_in[5];
    const float* W3 = (const float*)d_in[6];
    const float* Wh = (const float*)d_in[7];
    const float* bh = (const float*)d_in[8];
    float* out = (float*)d_out;

    int N = in_sizes[0] / 128;
    int E = in_sizes[1] / 2;

    char* p = (char*)d_ws;
    auto alloc = [&](size_t bytes) {
        char* r = p;
        p += (bytes + 255) & ~(size_t)255;
        return r;
    };
    int*      cnt     = (int*)alloc((size_t)N * 4);
    int*      row_ptr = (int*)alloc((size_t)(N + 1) * 4);
    int*      cursor  = (int*)alloc((size_t)N * 4);
    float*    dinv    = (float*)alloc((size_t)N * 4);
    int*      bsum    = (int*)alloc((size_t)1024 * 4);
    int*      boff    = (int*)alloc((size_t)1024 * 4);
    unsigned* csr     = (unsigned*)alloc((size_t)E * 4);
    _Float16* Wt      = (_Float16*)alloc((size_t)5 * 16384 * 2);
    _Float16* B0h     = (_Float16*)alloc((size_t)N * 128 * 2);
    _Float16* B1h     = (_Float16*)alloc((size_t)N * 128 * 2);
    _Float16* B2h     = (_Float16*)alloc((size_t)N * 128 * 2);

    const int* rowi = ei;
    const int* coli = ei + E;

    int nb = (N + SCAN_CHUNK - 1) / SCAN_CHUNK;
    int nzb = (N + 255) / 256;

    prep0_kernel<<<nzb + 80, 256, 0, stream>>>(cnt, N, nzb, W1, R1, W2, R2, W3, Wh, Wt);
    hist_kernel<<<(E + 255) / 256, 256, 0, stream>>>(coli, cnt, E);
    scan_reduce_kernel<<<nb, 256, 0, stream>>>(cnt, bsum, N);
    scan_bsum_kernel<<<1, 1024, 0, stream>>>(bsum, boff, nb);
    scan_write_kernel<<<nb, 256, 0, stream>>>(cnt, boff, row_ptr, cursor, dinv, N, E);
    fill_kernel<<<(E + 255) / 256, 256, 0, stream>>>(rowi, coli, dinv, cursor, csr, E);

    int gb = (N + 63) / 64;
    int sb = ((size_t)N * 16 + 255) / 256;
    _Float16* Wt1 = Wt;
    _Float16* Rt1 = Wt + 16384;
    _Float16* Wt2 = Wt + 2 * 16384;
    _Float16* Rt2 = Wt + 3 * 16384;
    _Float16* Wtc = Wt + 4 * 16384;

    // layer 1: H=B0h, XR=B1h (fp32 x converted in staging), x1 -> B1h
    gemm_dual_kernel<1><<<gb, 256, 0, stream>>>(x, Wt1, Rt1, B0h, B1h, N);
    spmm_kernel<1, 0><<<sb, 256, 0, stream>>>(B0h, B1h, row_ptr, csr, dinv,
                                              B1h, nullptr, nullptr, N);
    // layer 2: H=B0h, XR=B2h, x2 -> B2h
    gemm_dual_kernel<0><<<gb, 256, 0, stream>>>(B1h, Wt2, Rt2, B0h, B2h, N);
    spmm_kernel<1, 0><<<sb, 256, 0, stream>>>(B0h, B2h, row_ptr, csr, dinv,
                                              B2h, nullptr, nullptr, N);
    // layer 3 + head (linearity): G = x2@(W3@Wh); out = A@G + bh (fp32)
    gemm_h_kernel<<<gb, 256, 0, stream>>>(B2h, Wtc, B0h, N);
    spmm_kernel<0, 1><<<sb, 256, 0, stream>>>(B0h, nullptr, row_ptr, csr, dinv,
                                              nullptr, out, bh, N);
}